// Round 1
// 549.143 us; speedup vs baseline: 1.0066x; 1.0066x over previous
//
#include <hip/hip_runtime.h>
#include <hip/hip_bf16.h>
#include <cstdint>

typedef __bf16 bf16;
typedef __bf16 bf16x8 __attribute__((ext_vector_type(8)));
typedef float f32x4 __attribute__((ext_vector_type(4)));

#define DEV __device__ __forceinline__

DEV f32x4 mfma16(bf16x8 a, bf16x8 b, f32x4 c) {
  return __builtin_amdgcn_mfma_f32_16x16x32_bf16(a, b, c, 0, 0, 0);
}

DEV void gl2lds16(const void* g, void* l) {
  __builtin_amdgcn_global_load_lds((__attribute__((address_space(1))) void*)g,
                                   (__attribute__((address_space(3))) void*)l,
                                   16, 0, 0);
}

#define VMWAIT(N) asm volatile("s_waitcnt vmcnt(" #N ")" ::: "memory")

// ---------------- fused fp32 -> bf16 convert, 3 segments ----------------
DEV void cvt8(const float* __restrict__ s, bf16* __restrict__ d) {
  f32x4 a = *(const f32x4*)(s);
  f32x4 b = *(const f32x4*)(s + 4);
  bf16x8 o;
#pragma unroll
  for (int e = 0; e < 4; ++e) { o[e] = (bf16)a[e]; o[e + 4] = (bf16)b[e]; }
  *(bf16x8*)(d) = o;
}

__global__ void cvt3(const float* __restrict__ s0, bf16* __restrict__ d0, int n0,
                     const float* __restrict__ s1, bf16* __restrict__ d1, int n1,
                     const float* __restrict__ s2, bf16* __restrict__ d2) {
  long i = ((long)blockIdx.x * 256 + threadIdx.x) * 8;
  if (i < n0) { cvt8(s0 + i, d0 + i); return; }
  i -= n0;
  if (i < n1) { cvt8(s1 + i, d1 + i); return; }
  i -= n1;
  cvt8(s2 + i, d2 + i);
}

// ---------------- GEMM C = A(MxK) * B(NxK)^T ----------------
// 256x256 tile, 512 threads = 8 waves (2M x 4N), per-wave 128x64 output.
// Phase-pipelined: K split into K=32 slices; LDS = 4 rotating 32KiB regions
// (A 256x32 + B 256x32 each). Region p%4 is read at phase p; restaged during
// phase p+1 with data for phase p+4. 12 global_load_lds stay in flight;
// every phase waits only vmcnt(8) (counted, never a full drain in-loop).
// T2: 16B-chunk XOR swizzle slot^=(row>>1)&3, applied to global SOURCE addr
// (LDS dest stays linear for global_load_lds) and to ds_read addresses.
template <typename OutT, int SPLIT>
DEV void gemm256_body(const bf16* __restrict__ A, const bf16* __restrict__ B,
                      OutT* __restrict__ C, int M, int N, int K) {
  __shared__ char lds[131072];  // 4 regions x 32 KiB
  const int tid = threadIdx.x;
  const int lane = tid & 63, w = tid >> 6;
  const int wm = w >> 2, wn = w & 3;  // 2 x 4 waves
  const int quad = lane >> 4, r = lane & 15;
  const long mBase = (long)blockIdx.y * 256, nBase = (long)blockIdx.x * 256;
  const int Kh = K / SPLIT;
  const long kBeg = (long)blockIdx.z * Kh;
  const int G = Kh >> 5;  // number of K=32 phases

  // staging: region = 2048 16B chunks; thread stages chunks i*512+tid, i=0..3.
  // chunk c: part=c>>10 (0=A,1=B), row=(c>>2)&255, phys slot=c&3.
  // logical k-chunk at that phys slot = slot ^ ((row>>1)&3)  (swizzle).
  const bf16* src[4];
#pragma unroll
  for (int i = 0; i < 4; ++i) {
    const int c = i * 512 + tid;
    const int part = c >> 10, row = (c >> 2) & 255, slot = c & 3;
    const int kc = slot ^ ((row >> 1) & 3);
    const bf16* base = part ? (B + (nBase + row) * (long)K)
                            : (A + (mBase + row) * (long)K);
    src[i] = base + kBeg + kc * 8;
  }

  // fragment read offsets (bytes within a region); note (row>>1)&3 == (r>>1)&3
  // for all frag rows (wm*128, wn*64, mi*16, ni*16 are all 0 mod 8).
  const int pslot = (quad ^ ((r >> 1) & 3)) << 4;
  const int offA = (wm * 128 + r) * 64 + pslot;            // + mi*1024
  const int offB = 16384 + (wn * 64 + r) * 64 + pslot;     // + ni*1024

  f32x4 acc[8][4];
#pragma unroll
  for (int i = 0; i < 8; ++i)
#pragma unroll
    for (int j = 0; j < 4; ++j) acc[i][j] = f32x4{0.f, 0.f, 0.f, 0.f};

  auto stage = [&](int p) {
    char* db = lds + ((p & 3) << 15);
    const long ko = (long)p * 32;
#pragma unroll
    for (int i = 0; i < 4; ++i)
      gl2lds16(src[i] + ko, db + (i * 512 + w * 64) * 16);
  };

  auto phase = [&](int p, bool do_stage) {
    __builtin_amdgcn_s_barrier();          // all waves passed their vmcnt wait
    __builtin_amdgcn_sched_barrier(0);     // keep ds_reads below the barrier
    char* rb = lds + ((p & 3) << 15);
    bf16x8 af[8], bfr[4];
#pragma unroll
    for (int mi = 0; mi < 8; ++mi) af[mi] = *(const bf16x8*)(rb + offA + mi * 1024);
#pragma unroll
    for (int ni = 0; ni < 4; ++ni) bfr[ni] = *(const bf16x8*)(rb + offB + ni * 1024);
    if (do_stage) stage(p + 3);            // into region (p-1)&3, freed by this barrier
    asm volatile("s_waitcnt lgkmcnt(0)" ::: "memory");
    __builtin_amdgcn_sched_barrier(0);     // rule 18: pin MFMA below the wait
    __builtin_amdgcn_s_setprio(1);
#pragma unroll
    for (int mi = 0; mi < 8; ++mi)
#pragma unroll
      for (int ni = 0; ni < 4; ++ni)
        acc[mi][ni] = mfma16(af[mi], bfr[ni], acc[mi][ni]);
    __builtin_amdgcn_s_setprio(0);
  };

  // prologue: 3 regions (12 loads/thread) in flight
  stage(0); stage(1); stage(2);
  for (int p = 0; p < G - 3; ++p) { VMWAIT(8); phase(p, true); }
  VMWAIT(8); phase(G - 3, false);
  VMWAIT(4); phase(G - 2, false);
  VMWAIT(0); phase(G - 1, false);

  OutT* Cz = C + (size_t)blockIdx.z * M * N;
#pragma unroll
  for (int mi = 0; mi < 8; ++mi)
#pragma unroll
    for (int ni = 0; ni < 4; ++ni)
#pragma unroll
      for (int rg = 0; rg < 4; ++rg) {
        long row = mBase + wm * 128 + mi * 16 + quad * 4 + rg;
        long col = nBase + wn * 64 + ni * 16 + r;
        Cz[row * N + col] = (OutT)acc[mi][ni][rg];
      }
}

__global__ __launch_bounds__(512, 2) void gemm_qkv(const bf16* __restrict__ A,
                                                   const bf16* __restrict__ B,
                                                   bf16* __restrict__ C, int M, int N, int K) {
  gemm256_body<bf16, 1>(A, B, C, M, N, K);
}

__global__ __launch_bounds__(512, 2) void gemm_out2(const bf16* __restrict__ A,
                                                    const bf16* __restrict__ B,
                                                    float* __restrict__ C, int M, int N, int K) {
  gemm256_body<float, 2>(A, B, C, M, N, K);
}

// out = p0 + p1 (split-K reduction), 8 fp32/thread
__global__ void reduce_add(const float* __restrict__ p, float* __restrict__ o, int n) {
  const int i = (blockIdx.x * 256 + threadIdx.x) * 8;
  const f32x4 a0 = *(const f32x4*)(p + i),     b0 = *(const f32x4*)(p + n + i);
  const f32x4 a1 = *(const f32x4*)(p + i + 4), b1 = *(const f32x4*)(p + n + i + 4);
  *(f32x4*)(o + i) = a0 + b0;
  *(f32x4*)(o + i + 4) = a1 + b1;
}

// ---------------- RoPE (neox), vectorized bf16x8 ----------------
__global__ void rope_kernel(bf16* __restrict__ qkv, const int* __restrict__ pos) {
  int idx = blockIdx.x * 256 + threadIdx.x;  // T*40*8 threads
  int g = idx & 7;
  int rest = idx >> 3;
  int head = rest % 40;
  int t = rest / 40;
  bf16* p = qkv + (long)t * 6144 + head * 128 + g * 8;
  bf16x8 a = *(const bf16x8*)(p);
  bf16x8 b = *(const bf16x8*)(p + 64);
  const float pf = (float)pos[t];
  bf16x8 oa, ob;
#pragma unroll
  for (int e = 0; e < 8; ++e) {
    const int d = g * 8 + e;
    const float invf = __builtin_expf(-(float)d * (9.210340371976184f / 64.0f));
    const float fr = pf * invf;
    const float c = __builtin_cosf(fr), s = __builtin_sinf(fr);
    const float x1 = (float)a[e], x2 = (float)b[e];
    oa[e] = (bf16)(x1 * c - x2 * s);
    ob[e] = (bf16)(x2 * c + x1 * s);
  }
  *(bf16x8*)(p) = oa;
  *(bf16x8*)(p + 64) = ob;
}

// ---------------- flash attention v4: double-buffered LDS, 1 barrier/tile ----------------
__global__ __launch_bounds__(256, 2) void attn_kernel(const bf16* __restrict__ qkv,
                                                      bf16* __restrict__ out) {
  constexpr int LDV = 72, LDP = 72;
  constexpr float SCL2 = 0.08838834764831845f * 1.4426950408889634f;  // 1/sqrt(128)*log2(e)
  __shared__ bf16 Ks[2][64 * 128];   // [kv][d], chunk-XOR (phys = logical^(row&15))
  __shared__ bf16 Vt[2][128 * LDV];  // V^T [d][kv(+pad)], col-chunk XOR
  __shared__ bf16 Ps[64 * LDP];
  const int tid = threadIdx.x;
  const int lane = tid & 63, w = tid >> 6;
  const int quad = lane >> 4, r = lane & 15;
  const int pr = blockIdx.x, h = blockIdx.y;
  const int kvh = h >> 2;

  bf16x8 kreg[4], vreg[4];
  int srow[4], sdc[4];
#pragma unroll
  for (int ii = 0; ii < 4; ++ii) {
    const int c = ii * 256 + tid;
    srow[ii] = c >> 4;
    sdc[ii] = c & 15;
  }

  for (int which = 0; which < 2; ++which) {
    const int qt = which ? (31 - pr) : pr;
    const int rowq = qt * 64 + w * 16;

    bf16x8 qf[4];
#pragma unroll
    for (int ks = 0; ks < 4; ++ks)
      qf[ks] = *(const bf16x8*)(qkv + (long)(rowq + r) * 6144 + h * 128 + ks * 32 + quad * 8);

    f32x4 of[8];
#pragma unroll
    for (int di = 0; di < 8; ++di) of[di] = f32x4{0.f, 0.f, 0.f, 0.f};
    float mrun[4], lrun[4];
#pragma unroll
    for (int rg = 0; rg < 4; ++rg) { mrun[rg] = -__builtin_inff(); lrun[rg] = 0.f; }

    const int ntiles = qt + 1;
#pragma unroll
    for (int ii = 0; ii < 4; ++ii) {
      const long rb = (long)srow[ii] * 6144 + kvh * 128;
      kreg[ii] = *(const bf16x8*)(qkv + rb + 4096 + sdc[ii] * 8);
      vreg[ii] = *(const bf16x8*)(qkv + rb + 5120 + sdc[ii] * 8);
    }

    for (int kt = 0; kt < ntiles; ++kt) {
      const int kvbase = kt * 64;
      const int buf = kt & 1;
#pragma unroll
      for (int ii = 0; ii < 4; ++ii) {
        const int row = srow[ii], dc = sdc[ii];
        *(bf16x8*)(&Ks[buf][row * 128 + ((dc ^ (row & 15)) << 3)]) = kreg[ii];
        const int pc = (((row >> 3) ^ (dc & 7)) << 3) + (row & 7);
#pragma unroll
        for (int e = 0; e < 8; ++e) Vt[buf][(dc * 8 + e) * LDV + pc] = vreg[ii][e];
      }
      {
        const int kvn = (kt + 1 < ntiles) ? (kt + 1) * 64 : kt * 64;
#pragma unroll
        for (int ii = 0; ii < 4; ++ii) {
          const long rb = (long)(kvn + srow[ii]) * 6144 + kvh * 128;
          kreg[ii] = *(const bf16x8*)(qkv + rb + 4096 + sdc[ii] * 8);
          vreg[ii] = *(const bf16x8*)(qkv + rb + 5120 + sdc[ii] * 8);
        }
      }
      __syncthreads();  // the only barrier per tile

      f32x4 sacc[4];
#pragma unroll
      for (int ni = 0; ni < 4; ++ni) sacc[ni] = f32x4{0.f, 0.f, 0.f, 0.f};
#pragma unroll
      for (int ks = 0; ks < 4; ++ks) {
        bf16x8 kf[4];
#pragma unroll
        for (int ni = 0; ni < 4; ++ni)
          kf[ni] = *(const bf16x8*)(&Ks[buf][(ni * 16 + r) * 128 + (((ks * 4 + quad) ^ r) << 3)]);
#pragma unroll
        for (int ni = 0; ni < 4; ++ni) sacc[ni] = mfma16(qf[ks], kf[ni], sacc[ni]);
      }

      float mt[4];
#pragma unroll
      for (int rg = 0; rg < 4; ++rg) mt[rg] = -1e30f;
      if (kt == qt) {
        const int rq = rowq + quad * 4;
#pragma unroll
        for (int ni = 0; ni < 4; ++ni) {
          const int ck = kvbase + ni * 16 + r;
#pragma unroll
          for (int rg = 0; rg < 4; ++rg) {
            float sv = sacc[ni][rg];
            sv = (ck > rq + rg) ? -1e30f : sv;
            sacc[ni][rg] = sv;
            mt[rg] = fmaxf(mt[rg], sv);
          }
        }
      } else {
#pragma unroll
        for (int ni = 0; ni < 4; ++ni)
#pragma unroll
          for (int rg = 0; rg < 4; ++rg) mt[rg] = fmaxf(mt[rg], sacc[ni][rg]);
      }
#pragma unroll
      for (int rg = 0; rg < 4; ++rg) {
        float v = mt[rg];
        v = fmaxf(v, __shfl_xor(v, 1));
        v = fmaxf(v, __shfl_xor(v, 2));
        v = fmaxf(v, __shfl_xor(v, 4));
        v = fmaxf(v, __shfl_xor(v, 8));
        mt[rg] = v;
      }
      float alpha[4], rsum[4];
#pragma unroll
      for (int rg = 0; rg < 4; ++rg) {
        const float mnew = fmaxf(mrun[rg], mt[rg]);
        alpha[rg] = __builtin_exp2f((mrun[rg] - mnew) * SCL2);
        mrun[rg] = mnew;
        rsum[rg] = 0.f;
      }
#pragma unroll
      for (int ni = 0; ni < 4; ++ni)
#pragma unroll
        for (int rg = 0; rg < 4; ++rg) {
          const float pv = __builtin_exp2f((sacc[ni][rg] - mrun[rg]) * SCL2);
          rsum[rg] += pv;
          Ps[(w * 16 + quad * 4 + rg) * LDP + ni * 16 + r] = (bf16)pv;
        }
#pragma unroll
      for (int rg = 0; rg < 4; ++rg) {
        float v = rsum[rg];
        v += __shfl_xor(v, 1);
        v += __shfl_xor(v, 2);
        v += __shfl_xor(v, 4);
        v += __shfl_xor(v, 8);
        lrun[rg] = lrun[rg] * alpha[rg] + v;
      }
#pragma unroll
      for (int di = 0; di < 8; ++di)
#pragma unroll
        for (int rg = 0; rg < 4; ++rg) of[di][rg] *= alpha[rg];

#pragma unroll
      for (int js = 0; js < 2; ++js) {
        const bf16x8 pf = *(const bf16x8*)(&Ps[(w * 16 + r) * LDP + js * 32 + quad * 8]);
#pragma unroll
        for (int di = 0; di < 8; ++di) {
          const int vrow = di * 16 + r;
          const int vcol = (((js * 4 + quad) ^ ((vrow >> 3) & 7)) << 3);
          const bf16x8 vf = *(const bf16x8*)(&Vt[buf][vrow * LDV + vcol]);
          of[di] = mfma16(pf, vf, of[di]);
        }
      }
    }

#pragma unroll
    for (int rg = 0; rg < 4; ++rg) {
      const float inv = 1.f / lrun[rg];
      const long t = rowq + quad * 4 + rg;
#pragma unroll
      for (int di = 0; di < 8; ++di)
        out[t * 4096 + h * 128 + di * 16 + r] = (bf16)(of[di][rg] * inv);
    }
  }
}

// ---------------- host ----------------
extern "C" void kernel_launch(void* const* d_in, const int* in_sizes, int n_in,
                              void* d_out, int out_size, void* d_ws, size_t ws_size,
                              hipStream_t stream) {
  const int* positions = (const int*)d_in[0];
  const float* hidden = (const float*)d_in[1];
  const float* w_qkv = (const float*)d_in[2];
  const float* w_o = (const float*)d_in[3];
  float* out = (float*)d_out;

  char* ws = (char*)d_ws;
  bf16* hid_b  = (bf16*)(ws);                  // 2048x4096 bf16 (dead after gemm_qkv)
  bf16* wqkv_b = (bf16*)(ws + 16777216);       // 6144x4096 bf16 (dead after gemm_qkv)
  bf16* wo_b   = (bf16*)(ws + 67108864);       // 4096x4096 bf16
  bf16* qkv    = (bf16*)(ws + 100663296);      // 2048x6144 bf16
  bf16* attn   = (bf16*)(ws + 125829120);      // 2048x4096 bf16
  float* part  = (float*)(ws);                 // 2 x 2048x4096 fp32 partials (67.1 MB,
                                               // overlays hid_b/wqkv_b after they die)

  cvt3<<<24576, 256, 0, stream>>>(hidden, hid_b, 8388608,
                                  w_qkv, wqkv_b, 25165824,
                                  w_o, wo_b);
  gemm_qkv<<<dim3(24, 8), 512, 0, stream>>>(hid_b, wqkv_b, qkv, 2048, 6144, 4096);
  rope_kernel<<<2560, 256, 0, stream>>>(qkv, positions);
  attn_kernel<<<dim3(16, 32), 256, 0, stream>>>(qkv, attn);
  gemm_out2<<<dim3(16, 8, 2), 512, 0, stream>>>(attn, wo_b, part, 2048, 4096, 4096);
  reduce_add<<<4096, 256, 0, stream>>>(part, out, 8388608);
}

// Round 3
// 525.468 us; speedup vs baseline: 1.0519x; 1.0451x over previous
//
#include <hip/hip_runtime.h>
#include <hip/hip_bf16.h>
#include <cstdint>

typedef __bf16 bf16;
typedef __bf16 bf16x8 __attribute__((ext_vector_type(8)));
typedef float f32x4 __attribute__((ext_vector_type(4)));

#define DEV __device__ __forceinline__

DEV f32x4 mfma16(bf16x8 a, bf16x8 b, f32x4 c) {
  return __builtin_amdgcn_mfma_f32_16x16x32_bf16(a, b, c, 0, 0, 0);
}

DEV void gl2lds16(const void* g, void* l) {
  __builtin_amdgcn_global_load_lds((__attribute__((address_space(1))) void*)g,
                                   (__attribute__((address_space(3))) void*)l,
                                   16, 0, 0);
}

#define VMWAIT(N) asm volatile("s_waitcnt vmcnt(" #N ")" ::: "memory")

// ---------------- fused fp32 -> bf16 convert, 3 segments ----------------
DEV void cvt8(const float* __restrict__ s, bf16* __restrict__ d) {
  f32x4 a = *(const f32x4*)(s);
  f32x4 b = *(const f32x4*)(s + 4);
  bf16x8 o;
#pragma unroll
  for (int e = 0; e < 4; ++e) { o[e] = (bf16)a[e]; o[e + 4] = (bf16)b[e]; }
  *(bf16x8*)(d) = o;
}

__global__ void cvt3(const float* __restrict__ s0, bf16* __restrict__ d0, int n0,
                     const float* __restrict__ s1, bf16* __restrict__ d1, int n1,
                     const float* __restrict__ s2, bf16* __restrict__ d2) {
  long i = ((long)blockIdx.x * 256 + threadIdx.x) * 8;
  if (i < n0) { cvt8(s0 + i, d0 + i); return; }
  i -= n0;
  if (i < n1) { cvt8(s1 + i, d1 + i); return; }
  i -= n1;
  cvt8(s2 + i, d2 + i);
}

// ---------------- GEMM qkv: C = A(MxK) * B(NxK)^T, 256x256 tile ----------------
// 512 threads = 8 waves (2M x 4N), per-wave 128x64 output.
// Phase-pipelined: K split into K=32 slices; LDS = 4 rotating 32KiB regions.
// 12 global_load_lds in flight; every phase waits only vmcnt(8) (counted).
__global__ __launch_bounds__(512, 2) void gemm_qkv(const bf16* __restrict__ A,
                                                   const bf16* __restrict__ B,
                                                   bf16* __restrict__ C, int M, int N, int K) {
  __shared__ char lds[131072];  // 4 regions x 32 KiB
  const int tid = threadIdx.x;
  const int lane = tid & 63, w = tid >> 6;
  const int wm = w >> 2, wn = w & 3;  // 2 x 4 waves
  const int quad = lane >> 4, r = lane & 15;
  const long mBase = (long)blockIdx.y * 256, nBase = (long)blockIdx.x * 256;
  const int G = K >> 5;  // number of K=32 phases

  const bf16* src[4];
#pragma unroll
  for (int i = 0; i < 4; ++i) {
    const int c = i * 512 + tid;
    const int part = c >> 10, row = (c >> 2) & 255, slot = c & 3;
    const int kc = slot ^ ((row >> 1) & 3);
    const bf16* base = part ? (B + (nBase + row) * (long)K)
                            : (A + (mBase + row) * (long)K);
    src[i] = base + kc * 8;
  }

  const int pslot = (quad ^ ((r >> 1) & 3)) << 4;
  const int offA = (wm * 128 + r) * 64 + pslot;            // + mi*1024
  const int offB = 16384 + (wn * 64 + r) * 64 + pslot;     // + ni*1024

  f32x4 acc[8][4];
#pragma unroll
  for (int i = 0; i < 8; ++i)
#pragma unroll
    for (int j = 0; j < 4; ++j) acc[i][j] = f32x4{0.f, 0.f, 0.f, 0.f};

  auto stage = [&](int p) {
    char* db = lds + ((p & 3) << 15);
    const long ko = (long)p * 32;
#pragma unroll
    for (int i = 0; i < 4; ++i)
      gl2lds16(src[i] + ko, db + (i * 512 + w * 64) * 16);
  };

  auto phase = [&](int p, bool do_stage) {
    __builtin_amdgcn_s_barrier();
    __builtin_amdgcn_sched_barrier(0);
    char* rb = lds + ((p & 3) << 15);
    bf16x8 af[8], bfr[4];
#pragma unroll
    for (int mi = 0; mi < 8; ++mi) af[mi] = *(const bf16x8*)(rb + offA + mi * 1024);
#pragma unroll
    for (int ni = 0; ni < 4; ++ni) bfr[ni] = *(const bf16x8*)(rb + offB + ni * 1024);
    if (do_stage) stage(p + 3);
    asm volatile("s_waitcnt lgkmcnt(0)" ::: "memory");
    __builtin_amdgcn_sched_barrier(0);
    __builtin_amdgcn_s_setprio(1);
#pragma unroll
    for (int mi = 0; mi < 8; ++mi)
#pragma unroll
      for (int ni = 0; ni < 4; ++ni)
        acc[mi][ni] = mfma16(af[mi], bfr[ni], acc[mi][ni]);
    __builtin_amdgcn_s_setprio(0);
  };

  stage(0); stage(1); stage(2);
  for (int p = 0; p < G - 3; ++p) { VMWAIT(8); phase(p, true); }
  VMWAIT(8); phase(G - 3, false);
  VMWAIT(4); phase(G - 2, false);
  VMWAIT(0); phase(G - 1, false);

#pragma unroll
  for (int mi = 0; mi < 8; ++mi)
#pragma unroll
    for (int ni = 0; ni < 4; ++ni)
#pragma unroll
      for (int rg = 0; rg < 4; ++rg) {
        long row = mBase + wm * 128 + mi * 16 + quad * 4 + rg;
        long col = nBase + wn * 64 + ni * 16 + r;
        C[row * N + col] = (bf16)acc[mi][ni][rg];
      }
}

// ---------------- GEMM out: C(f32) = A(MxK) * B(NxK)^T, 128x256 tile ----------------
// Same pipeline, BM=128 BN=256 -> grid (16,16)=256 blocks (full CU coverage),
// SPLIT=1, f32 output written directly (no partials, no reduce_add).
// Region = A 128x32 (8 KiB) + B 256x32 (16 KiB) = 24 KiB; 4 regions = 96 KiB.
// 3 loads/thread/stage; 3 regions in flight -> steady wait vmcnt(6).
__global__ __launch_bounds__(512, 2) void gemm_out(const bf16* __restrict__ A,
                                                   const bf16* __restrict__ B,
                                                   float* __restrict__ C, int M, int N, int K) {
  __shared__ char lds[98304];
  const int tid = threadIdx.x;
  const int lane = tid & 63, w = tid >> 6;
  const int wm = w >> 2, wn = w & 3;  // 2 x 4 waves, per-wave 64x64
  const int quad = lane >> 4, r = lane & 15;
  const long mBase = (long)blockIdx.y * 128, nBase = (long)blockIdx.x * 256;
  const int G = K >> 5;

  const bf16* src[3];
#pragma unroll
  for (int i = 0; i < 3; ++i) {
    const int c = i * 512 + tid;
    const int partB = (c >= 512);
    const int rb = partB ? (c - 512) : c;   // A: [0,512), B: [0,1024)
    const int row = rb >> 2, slot = rb & 3;
    const int kc = slot ^ ((row >> 1) & 3);
    const bf16* base = partB ? (B + (nBase + row) * (long)K)
                             : (A + (mBase + row) * (long)K);
    src[i] = base + kc * 8;
  }

  const int pslot = (quad ^ ((r >> 1) & 3)) << 4;
  const int offA = (wm * 64 + r) * 64 + pslot;             // + mi*1024
  const int offB = 8192 + (wn * 64 + r) * 64 + pslot;      // + ni*1024

  f32x4 acc[4][4];
#pragma unroll
  for (int i = 0; i < 4; ++i)
#pragma unroll
    for (int j = 0; j < 4; ++j) acc[i][j] = f32x4{0.f, 0.f, 0.f, 0.f};

  auto stage = [&](int p) {
    char* db = lds + (p & 3) * 24576;
    const long ko = (long)p * 32;
    gl2lds16(src[0] + ko, db + (w * 64) * 16);
    gl2lds16(src[1] + ko, db + 8192 + (w * 64) * 16);
    gl2lds16(src[2] + ko, db + 8192 + (512 + w * 64) * 16);
  };

  auto phase = [&](int p, bool do_stage) {
    __builtin_amdgcn_s_barrier();
    __builtin_amdgcn_sched_barrier(0);
    char* rbuf = lds + (p & 3) * 24576;
    bf16x8 af[4], bfr[4];
#pragma unroll
    for (int mi = 0; mi < 4; ++mi) af[mi] = *(const bf16x8*)(rbuf + offA + mi * 1024);
#pragma unroll
    for (int ni = 0; ni < 4; ++ni) bfr[ni] = *(const bf16x8*)(rbuf + offB + ni * 1024);
    if (do_stage) stage(p + 3);
    asm volatile("s_waitcnt lgkmcnt(0)" ::: "memory");
    __builtin_amdgcn_sched_barrier(0);
    __builtin_amdgcn_s_setprio(1);
#pragma unroll
    for (int mi = 0; mi < 4; ++mi)
#pragma unroll
      for (int ni = 0; ni < 4; ++ni)
        acc[mi][ni] = mfma16(af[mi], bfr[ni], acc[mi][ni]);
    __builtin_amdgcn_s_setprio(0);
  };

  stage(0); stage(1); stage(2);
  for (int p = 0; p < G - 3; ++p) { VMWAIT(6); phase(p, true); }
  VMWAIT(6); phase(G - 3, false);
  VMWAIT(3); phase(G - 2, false);
  VMWAIT(0); phase(G - 1, false);

#pragma unroll
  for (int mi = 0; mi < 4; ++mi)
#pragma unroll
    for (int ni = 0; ni < 4; ++ni)
#pragma unroll
      for (int rg = 0; rg < 4; ++rg) {
        long row = mBase + wm * 64 + mi * 16 + quad * 4 + rg;
        long col = nBase + wn * 64 + ni * 16 + r;
        C[row * N + col] = acc[mi][ni][rg];
      }
}

// ---------------- RoPE (neox), vectorized bf16x8 ----------------
__global__ void rope_kernel(bf16* __restrict__ qkv, const int* __restrict__ pos) {
  int idx = blockIdx.x * 256 + threadIdx.x;  // T*40*8 threads
  int g = idx & 7;
  int rest = idx >> 3;
  int head = rest % 40;
  int t = rest / 40;
  bf16* p = qkv + (long)t * 6144 + head * 128 + g * 8;
  bf16x8 a = *(const bf16x8*)(p);
  bf16x8 b = *(const bf16x8*)(p + 64);
  const float pf = (float)pos[t];
  bf16x8 oa, ob;
#pragma unroll
  for (int e = 0; e < 8; ++e) {
    const int d = g * 8 + e;
    const float invf = __builtin_expf(-(float)d * (9.210340371976184f / 64.0f));
    const float fr = pf * invf;
    const float c = __builtin_cosf(fr), s = __builtin_sinf(fr);
    const float x1 = (float)a[e], x2 = (float)b[e];
    oa[e] = (bf16)(x1 * c - x2 * s);
    ob[e] = (bf16)(x2 * c + x1 * s);
  }
  *(bf16x8*)(p) = oa;
  *(bf16x8*)(p + 64) = ob;
}

// ---------------- flash attention v4 + setprio: double-buffered LDS ----------------
__global__ __launch_bounds__(256, 2) void attn_kernel(const bf16* __restrict__ qkv,
                                                      bf16* __restrict__ out) {
  constexpr int LDV = 72, LDP = 72;
  constexpr float SCL2 = 0.08838834764831845f * 1.4426950408889634f;  // 1/sqrt(128)*log2(e)
  __shared__ bf16 Ks[2][64 * 128];   // [kv][d], chunk-XOR (phys = logical^(row&15))
  __shared__ bf16 Vt[2][128 * LDV];  // V^T [d][kv(+pad)], col-chunk XOR
  __shared__ bf16 Ps[64 * LDP];
  const int tid = threadIdx.x;
  const int lane = tid & 63, w = tid >> 6;
  const int quad = lane >> 4, r = lane & 15;
  const int pr = blockIdx.x, h = blockIdx.y;
  const int kvh = h >> 2;

  bf16x8 kreg[4], vreg[4];
  int srow[4], sdc[4];
#pragma unroll
  for (int ii = 0; ii < 4; ++ii) {
    const int c = ii * 256 + tid;
    srow[ii] = c >> 4;
    sdc[ii] = c & 15;
  }

  for (int which = 0; which < 2; ++which) {
    const int qt = which ? (31 - pr) : pr;
    const int rowq = qt * 64 + w * 16;

    bf16x8 qf[4];
#pragma unroll
    for (int ks = 0; ks < 4; ++ks)
      qf[ks] = *(const bf16x8*)(qkv + (long)(rowq + r) * 6144 + h * 128 + ks * 32 + quad * 8);

    f32x4 of[8];
#pragma unroll
    for (int di = 0; di < 8; ++di) of[di] = f32x4{0.f, 0.f, 0.f, 0.f};
    float mrun[4], lrun[4];
#pragma unroll
    for (int rg = 0; rg < 4; ++rg) { mrun[rg] = -__builtin_inff(); lrun[rg] = 0.f; }

    const int ntiles = qt + 1;
#pragma unroll
    for (int ii = 0; ii < 4; ++ii) {
      const long rb = (long)srow[ii] * 6144 + kvh * 128;
      kreg[ii] = *(const bf16x8*)(qkv + rb + 4096 + sdc[ii] * 8);
      vreg[ii] = *(const bf16x8*)(qkv + rb + 5120 + sdc[ii] * 8);
    }

    for (int kt = 0; kt < ntiles; ++kt) {
      const int kvbase = kt * 64;
      const int buf = kt & 1;
#pragma unroll
      for (int ii = 0; ii < 4; ++ii) {
        const int row = srow[ii], dc = sdc[ii];
        *(bf16x8*)(&Ks[buf][row * 128 + ((dc ^ (row & 15)) << 3)]) = kreg[ii];
        const int pc = (((row >> 3) ^ (dc & 7)) << 3) + (row & 7);
#pragma unroll
        for (int e = 0; e < 8; ++e) Vt[buf][(dc * 8 + e) * LDV + pc] = vreg[ii][e];
      }
      {
        const int kvn = (kt + 1 < ntiles) ? (kt + 1) * 64 : kt * 64;
#pragma unroll
        for (int ii = 0; ii < 4; ++ii) {
          const long rb = (long)(kvn + srow[ii]) * 6144 + kvh * 128;
          kreg[ii] = *(const bf16x8*)(qkv + rb + 4096 + sdc[ii] * 8);
          vreg[ii] = *(const bf16x8*)(qkv + rb + 5120 + sdc[ii] * 8);
        }
      }
      __syncthreads();  // the only barrier per tile

      f32x4 sacc[4];
#pragma unroll
      for (int ni = 0; ni < 4; ++ni) sacc[ni] = f32x4{0.f, 0.f, 0.f, 0.f};
      __builtin_amdgcn_s_setprio(1);
#pragma unroll
      for (int ks = 0; ks < 4; ++ks) {
        bf16x8 kf[4];
#pragma unroll
        for (int ni = 0; ni < 4; ++ni)
          kf[ni] = *(const bf16x8*)(&Ks[buf][(ni * 16 + r) * 128 + (((ks * 4 + quad) ^ r) << 3)]);
#pragma unroll
        for (int ni = 0; ni < 4; ++ni) sacc[ni] = mfma16(qf[ks], kf[ni], sacc[ni]);
      }
      __builtin_amdgcn_s_setprio(0);

      float mt[4];
#pragma unroll
      for (int rg = 0; rg < 4; ++rg) mt[rg] = -1e30f;
      if (kt == qt) {
        const int rq = rowq + quad * 4;
#pragma unroll
        for (int ni = 0; ni < 4; ++ni) {
          const int ck = kvbase + ni * 16 + r;
#pragma unroll
          for (int rg = 0; rg < 4; ++rg) {
            float sv = sacc[ni][rg];
            sv = (ck > rq + rg) ? -1e30f : sv;
            sacc[ni][rg] = sv;
            mt[rg] = fmaxf(mt[rg], sv);
          }
        }
      } else {
#pragma unroll
        for (int ni = 0; ni < 4; ++ni)
#pragma unroll
          for (int rg = 0; rg < 4; ++rg) mt[rg] = fmaxf(mt[rg], sacc[ni][rg]);
      }
#pragma unroll
      for (int rg = 0; rg < 4; ++rg) {
        float v = mt[rg];
        v = fmaxf(v, __shfl_xor(v, 1));
        v = fmaxf(v, __shfl_xor(v, 2));
        v = fmaxf(v, __shfl_xor(v, 4));
        v = fmaxf(v, __shfl_xor(v, 8));
        mt[rg] = v;
      }
      float alpha[4], rsum[4];
#pragma unroll
      for (int rg = 0; rg < 4; ++rg) {
        const float mnew = fmaxf(mrun[rg], mt[rg]);
        alpha[rg] = __builtin_exp2f((mrun[rg] - mnew) * SCL2);
        mrun[rg] = mnew;
        rsum[rg] = 0.f;
      }
#pragma unroll
      for (int ni = 0; ni < 4; ++ni)
#pragma unroll
        for (int rg = 0; rg < 4; ++rg) {
          const float pv = __builtin_exp2f((sacc[ni][rg] - mrun[rg]) * SCL2);
          rsum[rg] += pv;
          Ps[(w * 16 + quad * 4 + rg) * LDP + ni * 16 + r] = (bf16)pv;
        }
#pragma unroll
      for (int rg = 0; rg < 4; ++rg) {
        float v = rsum[rg];
        v += __shfl_xor(v, 1);
        v += __shfl_xor(v, 2);
        v += __shfl_xor(v, 4);
        v += __shfl_xor(v, 8);
        lrun[rg] = lrun[rg] * alpha[rg] + v;
      }
#pragma unroll
      for (int di = 0; di < 8; ++di)
#pragma unroll
        for (int rg = 0; rg < 4; ++rg) of[di][rg] *= alpha[rg];

      __builtin_amdgcn_s_setprio(1);
#pragma unroll
      for (int js = 0; js < 2; ++js) {
        const bf16x8 pf = *(const bf16x8*)(&Ps[(w * 16 + r) * LDP + js * 32 + quad * 8]);
#pragma unroll
        for (int di = 0; di < 8; ++di) {
          const int vrow = di * 16 + r;
          const int vcol = (((js * 4 + quad) ^ ((vrow >> 3) & 7)) << 3);
          const bf16x8 vf = *(const bf16x8*)(&Vt[buf][vrow * LDV + vcol]);
          of[di] = mfma16(pf, vf, of[di]);
        }
      }
      __builtin_amdgcn_s_setprio(0);
    }

#pragma unroll
    for (int rg = 0; rg < 4; ++rg) {
      const float inv = 1.f / lrun[rg];
      const long t = rowq + quad * 4 + rg;
#pragma unroll
      for (int di = 0; di < 8; ++di)
        out[t * 4096 + h * 128 + di * 16 + r] = (bf16)(of[di][rg] * inv);
    }
  }
}

// ---------------- host ----------------
extern "C" void kernel_launch(void* const* d_in, const int* in_sizes, int n_in,
                              void* d_out, int out_size, void* d_ws, size_t ws_size,
                              hipStream_t stream) {
  const int* positions = (const int*)d_in[0];
  const float* hidden = (const float*)d_in[1];
  const float* w_qkv = (const float*)d_in[2];
  const float* w_o = (const float*)d_in[3];
  float* out = (float*)d_out;

  char* ws = (char*)d_ws;
  bf16* hid_b  = (bf16*)(ws);                  // 2048x4096 bf16 (dead after gemm_qkv)
  bf16* wqkv_b = (bf16*)(ws + 16777216);       // 6144x4096 bf16 (dead after gemm_qkv)
  bf16* wo_b   = (bf16*)(ws + 67108864);       // 4096x4096 bf16
  bf16* qkv    = (bf16*)(ws + 100663296);      // 2048x6144 bf16
  bf16* attn   = (bf16*)(ws + 125829120);      // 2048x4096 bf16

  cvt3<<<24576, 256, 0, stream>>>(hidden, hid_b, 8388608,
                                  w_qkv, wqkv_b, 25165824,
                                  w_o, wo_b);
  gemm_qkv<<<dim3(24, 8), 512, 0, stream>>>(hid_b, wqkv_b, qkv, 2048, 6144, 4096);
  rope_kernel<<<2560, 256, 0, stream>>>(qkv, positions);
  attn_kernel<<<dim3(16, 32), 256, 0, stream>>>(qkv, attn);
  gemm_out<<<dim3(16, 16), 512, 0, stream>>>(attn, wo_b, out, 2048, 4096, 4096);
}

// Round 5
// 505.536 us; speedup vs baseline: 1.0934x; 1.0394x over previous
//
#include <hip/hip_runtime.h>
#include <hip/hip_bf16.h>
#include <cstdint>

typedef __bf16 bf16;
typedef __bf16 bf16x8 __attribute__((ext_vector_type(8)));
typedef float f32x4 __attribute__((ext_vector_type(4)));

#define DEV __device__ __forceinline__

DEV f32x4 mfma16(bf16x8 a, bf16x8 b, f32x4 c) {
  return __builtin_amdgcn_mfma_f32_16x16x32_bf16(a, b, c, 0, 0, 0);
}

DEV void gl2lds16(const void* g, void* l) {
  __builtin_amdgcn_global_load_lds((__attribute__((address_space(1))) void*)g,
                                   (__attribute__((address_space(3))) void*)l,
                                   16, 0, 0);
}

#define VMWAIT(N) asm volatile("s_waitcnt vmcnt(" #N ")" ::: "memory")

// ---------------- fused fp32 -> bf16 convert, 3 segments ----------------
DEV void cvt8(const float* __restrict__ s, bf16* __restrict__ d) {
  f32x4 a = *(const f32x4*)(s);
  f32x4 b = *(const f32x4*)(s + 4);
  bf16x8 o;
#pragma unroll
  for (int e = 0; e < 4; ++e) { o[e] = (bf16)a[e]; o[e + 4] = (bf16)b[e]; }
  *(bf16x8*)(d) = o;
}

__global__ void cvt3(const float* __restrict__ s0, bf16* __restrict__ d0, int n0,
                     const float* __restrict__ s1, bf16* __restrict__ d1, int n1,
                     const float* __restrict__ s2, bf16* __restrict__ d2) {
  long i = ((long)blockIdx.x * 256 + threadIdx.x) * 8;
  if (i < n0) { cvt8(s0 + i, d0 + i); return; }
  i -= n0;
  if (i < n1) { cvt8(s1 + i, d1 + i); return; }
  i -= n1;
  cvt8(s2 + i, d2 + i);
}

// ---------------- GEMM qkv: C = A(MxK) * B(NxK)^T, 128x384 tile ----------------
// grid (16,16) = 256 blocks = exactly 1 per CU (was 192/256 = 75% coverage).
// 512 threads = 8 waves (2M x 4N), per-wave 64x96 output (acc[4][6]).
// Phase-pipelined: K=32 slices; LDS = 4 rotating 32KiB regions (A 128x32 = 8KB,
// B 384x32 = 24KB). 4 loads/thread/stage, 3 regions in flight -> vmcnt(8).
__global__ __launch_bounds__(512, 2) void gemm_qkv(const bf16* __restrict__ A,
                                                   const bf16* __restrict__ B,
                                                   bf16* __restrict__ C, int M, int N, int K) {
  __shared__ char lds[131072];  // 4 regions x 32 KiB
  const int tid = threadIdx.x;
  const int lane = tid & 63, w = tid >> 6;
  const int wm = w >> 2, wn = w & 3;  // 2 x 4 waves
  const int quad = lane >> 4, r = lane & 15;
  const long mBase = (long)blockIdx.y * 128, nBase = (long)blockIdx.x * 384;
  const int G = K >> 5;  // number of K=32 phases

  // region = 2048 16B chunks: A chunks [0,512): row=c>>2; B chunks [512,2048):
  // row=(c-512)>>2.  phys slot=c&3, logical k-chunk = slot ^ ((row>>1)&3).
  const bf16* src[4];
#pragma unroll
  for (int i = 0; i < 4; ++i) {
    const int c = i * 512 + tid;
    const int partB = (c >= 512);
    const int rb = partB ? (c - 512) : c;
    const int row = rb >> 2, slot = rb & 3;
    const int kc = slot ^ ((row >> 1) & 3);
    const bf16* base = partB ? (B + (nBase + row) * (long)K)
                             : (A + (mBase + row) * (long)K);
    src[i] = base + kc * 8;
  }

  const int pslot = (quad ^ ((r >> 1) & 3)) << 4;
  const int offA = (wm * 64 + r) * 64 + pslot;                 // + mi*1024
  const int offB = 8192 + (wn * 96 + r) * 64 + pslot;          // + ni*1024

  f32x4 acc[4][6];
#pragma unroll
  for (int i = 0; i < 4; ++i)
#pragma unroll
    for (int j = 0; j < 6; ++j) acc[i][j] = f32x4{0.f, 0.f, 0.f, 0.f};

  auto stage = [&](int p) {
    char* db = lds + ((p & 3) << 15);
    const long ko = (long)p * 32;
#pragma unroll
    for (int i = 0; i < 4; ++i)
      gl2lds16(src[i] + ko, db + (i * 512 + w * 64) * 16);
  };

  auto phase = [&](int p, bool do_stage) {
    __builtin_amdgcn_s_barrier();
    __builtin_amdgcn_sched_barrier(0);
    char* rb = lds + ((p & 3) << 15);
    bf16x8 af[4], bfr[6];
#pragma unroll
    for (int mi = 0; mi < 4; ++mi) af[mi] = *(const bf16x8*)(rb + offA + mi * 1024);
#pragma unroll
    for (int ni = 0; ni < 6; ++ni) bfr[ni] = *(const bf16x8*)(rb + offB + ni * 1024);
    if (do_stage) stage(p + 3);
    asm volatile("s_waitcnt lgkmcnt(0)" ::: "memory");
    __builtin_amdgcn_sched_barrier(0);
    __builtin_amdgcn_s_setprio(1);
#pragma unroll
    for (int mi = 0; mi < 4; ++mi)
#pragma unroll
      for (int ni = 0; ni < 6; ++ni)
        acc[mi][ni] = mfma16(af[mi], bfr[ni], acc[mi][ni]);
    __builtin_amdgcn_s_setprio(0);
  };

  stage(0); stage(1); stage(2);
  for (int p = 0; p < G - 3; ++p) { VMWAIT(8); phase(p, true); }
  VMWAIT(8); phase(G - 3, false);
  VMWAIT(4); phase(G - 2, false);
  VMWAIT(0); phase(G - 1, false);

#pragma unroll
  for (int mi = 0; mi < 4; ++mi)
#pragma unroll
    for (int ni = 0; ni < 6; ++ni)
#pragma unroll
      for (int rg = 0; rg < 4; ++rg) {
        long row = mBase + wm * 64 + mi * 16 + quad * 4 + rg;
        long col = nBase + wn * 96 + ni * 16 + r;
        C[row * N + col] = (bf16)acc[mi][ni][rg];
      }
}

// ---------------- GEMM out: C(f32) = A(MxK) * B(NxK)^T, 128x256 tile ----------------
// grid (16,16)=256 blocks, SPLIT=1, f32 output direct.
// Region = A 128x32 (8 KiB) + B 256x32 (16 KiB) = 24 KiB; 4 regions = 96 KiB.
// 3 loads/thread/stage; 3 regions in flight -> steady wait vmcnt(6).
__global__ __launch_bounds__(512, 2) void gemm_out(const bf16* __restrict__ A,
                                                   const bf16* __restrict__ B,
                                                   float* __restrict__ C, int M, int N, int K) {
  __shared__ char lds[98304];
  const int tid = threadIdx.x;
  const int lane = tid & 63, w = tid >> 6;
  const int wm = w >> 2, wn = w & 3;  // 2 x 4 waves, per-wave 64x64
  const int quad = lane >> 4, r = lane & 15;
  const long mBase = (long)blockIdx.y * 128, nBase = (long)blockIdx.x * 256;
  const int G = K >> 5;

  const bf16* src[3];
#pragma unroll
  for (int i = 0; i < 3; ++i) {
    const int c = i * 512 + tid;
    const int partB = (c >= 512);
    const int rb = partB ? (c - 512) : c;   // A: [0,512), B: [0,1024)
    const int row = rb >> 2, slot = rb & 3;
    const int kc = slot ^ ((row >> 1) & 3);
    const bf16* base = partB ? (B + (nBase + row) * (long)K)
                             : (A + (mBase + row) * (long)K);
    src[i] = base + kc * 8;
  }

  const int pslot = (quad ^ ((r >> 1) & 3)) << 4;
  const int offA = (wm * 64 + r) * 64 + pslot;             // + mi*1024
  const int offB = 8192 + (wn * 64 + r) * 64 + pslot;      // + ni*1024

  f32x4 acc[4][4];
#pragma unroll
  for (int i = 0; i < 4; ++i)
#pragma unroll
    for (int j = 0; j < 4; ++j) acc[i][j] = f32x4{0.f, 0.f, 0.f, 0.f};

  auto stage = [&](int p) {
    char* db = lds + (p & 3) * 24576;
    const long ko = (long)p * 32;
    gl2lds16(src[0] + ko, db + (w * 64) * 16);
    gl2lds16(src[1] + ko, db + 8192 + (w * 64) * 16);
    gl2lds16(src[2] + ko, db + 8192 + (512 + w * 64) * 16);
  };

  auto phase = [&](int p, bool do_stage) {
    __builtin_amdgcn_s_barrier();
    __builtin_amdgcn_sched_barrier(0);
    char* rbuf = lds + (p & 3) * 24576;
    bf16x8 af[4], bfr[4];
#pragma unroll
    for (int mi = 0; mi < 4; ++mi) af[mi] = *(const bf16x8*)(rbuf + offA + mi * 1024);
#pragma unroll
    for (int ni = 0; ni < 4; ++ni) bfr[ni] = *(const bf16x8*)(rbuf + offB + ni * 1024);
    if (do_stage) stage(p + 3);
    asm volatile("s_waitcnt lgkmcnt(0)" ::: "memory");
    __builtin_amdgcn_sched_barrier(0);
    __builtin_amdgcn_s_setprio(1);
#pragma unroll
    for (int mi = 0; mi < 4; ++mi)
#pragma unroll
      for (int ni = 0; ni < 4; ++ni)
        acc[mi][ni] = mfma16(af[mi], bfr[ni], acc[mi][ni]);
    __builtin_amdgcn_s_setprio(0);
  };

  stage(0); stage(1); stage(2);
  for (int p = 0; p < G - 3; ++p) { VMWAIT(6); phase(p, true); }
  VMWAIT(6); phase(G - 3, false);
  VMWAIT(3); phase(G - 2, false);
  VMWAIT(0); phase(G - 1, false);

#pragma unroll
  for (int mi = 0; mi < 4; ++mi)
#pragma unroll
    for (int ni = 0; ni < 4; ++ni)
#pragma unroll
      for (int rg = 0; rg < 4; ++rg) {
        long row = mBase + wm * 64 + mi * 16 + quad * 4 + rg;
        long col = nBase + wn * 64 + ni * 16 + r;
        C[row * N + col] = acc[mi][ni][rg];
      }
}

// ---------------- RoPE (neox), vectorized bf16x8 ----------------
__global__ void rope_kernel(bf16* __restrict__ qkv, const int* __restrict__ pos) {
  int idx = blockIdx.x * 256 + threadIdx.x;  // T*40*8 threads
  int g = idx & 7;
  int rest = idx >> 3;
  int head = rest % 40;
  int t = rest / 40;
  bf16* p = qkv + (long)t * 6144 + head * 128 + g * 8;
  bf16x8 a = *(const bf16x8*)(p);
  bf16x8 b = *(const bf16x8*)(p + 64);
  const float pf = (float)pos[t];
  bf16x8 oa, ob;
#pragma unroll
  for (int e = 0; e < 8; ++e) {
    const int d = g * 8 + e;
    const float invf = __builtin_expf(-(float)d * (9.210340371976184f / 64.0f));
    const float fr = pf * invf;
    const float c = __builtin_cosf(fr), s = __builtin_sinf(fr);
    const float x1 = (float)a[e], x2 = (float)b[e];
    oa[e] = (bf16)(x1 * c - x2 * s);
    ob[e] = (bf16)(x2 * c + x1 * s);
  }
  *(bf16x8*)(p) = oa;
  *(bf16x8*)(p + 64) = ob;
}

// ---------------- flash attention v6b: QBLK=128, 8 waves, defer-max ----------------
// 512 threads, grid (8,32). Each block: 2 q-chunks of 128 rows (qc = pr and
// 15-pr; 34 kv-tiles total per block, uniform). Mask predicate fixed vs v6:
// mask whenever tile max kv exceeds the wave's FIRST row (kvbase+63 > rowq),
// not its last row -- v6 leaked future kv for waves 3 and 7 at diagonal tiles.
__global__ __launch_bounds__(512, 2) void attn_kernel(const bf16* __restrict__ qkv,
                                                      bf16* __restrict__ out) {
  constexpr int LDV = 72, LDP = 72;
  constexpr float SCL2 = 0.08838834764831845f * 1.4426950408889634f;  // 1/sqrt(128)*log2(e)
  __shared__ bf16 Ks[2][64 * 128];   // [kv][d], chunk-XOR (phys = logical^(row&15))
  __shared__ bf16 Vt[2][128 * LDV];  // V^T [d][kv(+pad)], col-chunk XOR
  __shared__ bf16 Ps[128 * LDP];
  const int tid = threadIdx.x;
  const int lane = tid & 63, w = tid >> 6;
  const int quad = lane >> 4, r = lane & 15;
  const int pr = blockIdx.x, h = blockIdx.y;
  const int kvh = h >> 2;

  bf16x8 kreg[2], vreg[2];
  int srow[2], sdc[2];
#pragma unroll
  for (int ii = 0; ii < 2; ++ii) {
    const int c = ii * 512 + tid;   // 1024 chunks of 8 bf16 cover 64x128
    srow[ii] = c >> 4;
    sdc[ii] = c & 15;
  }

  for (int which = 0; which < 2; ++which) {
    const int qc = which ? (15 - pr) : pr;
    const int rowq = qc * 128 + w * 16;

    bf16x8 qf[4];
#pragma unroll
    for (int ks = 0; ks < 4; ++ks)
      qf[ks] = *(const bf16x8*)(qkv + (long)(rowq + r) * 6144 + h * 128 + ks * 32 + quad * 8);

    f32x4 of[8];
#pragma unroll
    for (int di = 0; di < 8; ++di) of[di] = f32x4{0.f, 0.f, 0.f, 0.f};
    float mrun[4], lrun[4];
#pragma unroll
    for (int rg = 0; rg < 4; ++rg) { mrun[rg] = -__builtin_inff(); lrun[rg] = 0.f; }

    const int ntiles = 2 * qc + 2;
#pragma unroll
    for (int ii = 0; ii < 2; ++ii) {
      const long rb = (long)srow[ii] * 6144 + kvh * 128;
      kreg[ii] = *(const bf16x8*)(qkv + rb + 4096 + sdc[ii] * 8);
      vreg[ii] = *(const bf16x8*)(qkv + rb + 5120 + sdc[ii] * 8);
    }

    for (int kt = 0; kt < ntiles; ++kt) {
      const int kvbase = kt * 64;
      const int buf = kt & 1;
#pragma unroll
      for (int ii = 0; ii < 2; ++ii) {
        const int row = srow[ii], dc = sdc[ii];
        *(bf16x8*)(&Ks[buf][row * 128 + ((dc ^ (row & 15)) << 3)]) = kreg[ii];
        const int pc = (((row >> 3) ^ (dc & 7)) << 3) + (row & 7);
#pragma unroll
        for (int e = 0; e < 8; ++e) Vt[buf][(dc * 8 + e) * LDV + pc] = vreg[ii][e];
      }
      {
        const int kvn = (kt + 1 < ntiles) ? (kt + 1) * 64 : kt * 64;
#pragma unroll
        for (int ii = 0; ii < 2; ++ii) {
          const long rb = (long)(kvn + srow[ii]) * 6144 + kvh * 128;
          kreg[ii] = *(const bf16x8*)(qkv + rb + 4096 + sdc[ii] * 8);
          vreg[ii] = *(const bf16x8*)(qkv + rb + 5120 + sdc[ii] * 8);
        }
      }
      __syncthreads();  // the only barrier per tile

      f32x4 sacc[4];
#pragma unroll
      for (int ni = 0; ni < 4; ++ni) sacc[ni] = f32x4{0.f, 0.f, 0.f, 0.f};
      __builtin_amdgcn_s_setprio(1);
#pragma unroll
      for (int ks = 0; ks < 4; ++ks) {
        bf16x8 kf[4];
#pragma unroll
        for (int ni = 0; ni < 4; ++ni)
          kf[ni] = *(const bf16x8*)(&Ks[buf][(ni * 16 + r) * 128 + (((ks * 4 + quad) ^ r) << 3)]);
#pragma unroll
        for (int ni = 0; ni < 4; ++ni) sacc[ni] = mfma16(qf[ks], kf[ni], sacc[ni]);
      }
      __builtin_amdgcn_s_setprio(0);

      float mt[4];
#pragma unroll
      for (int rg = 0; rg < 4; ++rg) mt[rg] = -1e30f;
      if (kvbase + 63 > rowq) {  // tile max kv exceeds wave's first row: mask
        const int rq = rowq + quad * 4;
#pragma unroll
        for (int ni = 0; ni < 4; ++ni) {
          const int ck = kvbase + ni * 16 + r;
#pragma unroll
          for (int rg = 0; rg < 4; ++rg) {
            float sv = sacc[ni][rg];
            sv = (ck > rq + rg) ? -1e30f : sv;
            sacc[ni][rg] = sv;
            mt[rg] = fmaxf(mt[rg], sv);
          }
        }
      } else {
#pragma unroll
        for (int ni = 0; ni < 4; ++ni)
#pragma unroll
          for (int rg = 0; rg < 4; ++rg) mt[rg] = fmaxf(mt[rg], sacc[ni][rg]);
      }
#pragma unroll
      for (int rg = 0; rg < 4; ++rg) {
        float v = mt[rg];
        v = fmaxf(v, __shfl_xor(v, 1));
        v = fmaxf(v, __shfl_xor(v, 2));
        v = fmaxf(v, __shfl_xor(v, 4));
        v = fmaxf(v, __shfl_xor(v, 8));
        mt[rg] = v;
      }
      // T13 defer-max: skip O/l rescale unless the tile max grew past THR=10
      // (pre-scale logits; P then bounded by 2^(10*SCL2) ~ 2.4 -- bf16-safe).
      const bool grew = (mt[0] > mrun[0] + 10.f) || (mt[1] > mrun[1] + 10.f) ||
                        (mt[2] > mrun[2] + 10.f) || (mt[3] > mrun[3] + 10.f);
      if (__any(grew)) {
        float alpha[4];
#pragma unroll
        for (int rg = 0; rg < 4; ++rg) {
          const float mnew = fmaxf(mrun[rg], mt[rg]);
          alpha[rg] = __builtin_exp2f((mrun[rg] - mnew) * SCL2);
          mrun[rg] = mnew;
          lrun[rg] *= alpha[rg];
        }
#pragma unroll
        for (int di = 0; di < 8; ++di)
#pragma unroll
          for (int rg = 0; rg < 4; ++rg) of[di][rg] *= alpha[rg];
      }
      float rsum[4];
#pragma unroll
      for (int rg = 0; rg < 4; ++rg) rsum[rg] = 0.f;
#pragma unroll
      for (int ni = 0; ni < 4; ++ni)
#pragma unroll
        for (int rg = 0; rg < 4; ++rg) {
          const float pv = __builtin_exp2f((sacc[ni][rg] - mrun[rg]) * SCL2);
          rsum[rg] += pv;
          Ps[(w * 16 + quad * 4 + rg) * LDP + ni * 16 + r] = (bf16)pv;
        }
#pragma unroll
      for (int rg = 0; rg < 4; ++rg) {
        float v = rsum[rg];
        v += __shfl_xor(v, 1);
        v += __shfl_xor(v, 2);
        v += __shfl_xor(v, 4);
        v += __shfl_xor(v, 8);
        lrun[rg] += v;
      }

      __builtin_amdgcn_s_setprio(1);
#pragma unroll
      for (int js = 0; js < 2; ++js) {
        const bf16x8 pf = *(const bf16x8*)(&Ps[(w * 16 + r) * LDP + js * 32 + quad * 8]);
#pragma unroll
        for (int di = 0; di < 8; ++di) {
          const int vrow = di * 16 + r;
          const int vcol = (((js * 4 + quad) ^ ((vrow >> 3) & 7)) << 3);
          const bf16x8 vf = *(const bf16x8*)(&Vt[buf][vrow * LDV + vcol]);
          of[di] = mfma16(pf, vf, of[di]);
        }
      }
      __builtin_amdgcn_s_setprio(0);
    }

#pragma unroll
    for (int rg = 0; rg < 4; ++rg) {
      const float inv = 1.f / lrun[rg];
      const long t = rowq + quad * 4 + rg;
#pragma unroll
      for (int di = 0; di < 8; ++di)
        out[t * 4096 + h * 128 + di * 16 + r] = (bf16)(of[di][rg] * inv);
    }
    __syncthreads();  // chunk boundary: all reads of LDS buffers done before restaging
  }
}

// ---------------- host ----------------
extern "C" void kernel_launch(void* const* d_in, const int* in_sizes, int n_in,
                              void* d_out, int out_size, void* d_ws, size_t ws_size,
                              hipStream_t stream) {
  const int* positions = (const int*)d_in[0];
  const float* hidden = (const float*)d_in[1];
  const float* w_qkv = (const float*)d_in[2];
  const float* w_o = (const float*)d_in[3];
  float* out = (float*)d_out;

  char* ws = (char*)d_ws;
  bf16* hid_b  = (bf16*)(ws);                  // 2048x4096 bf16 (dead after gemm_qkv)
  bf16* wqkv_b = (bf16*)(ws + 16777216);       // 6144x4096 bf16 (dead after gemm_qkv)
  bf16* wo_b   = (bf16*)(ws + 67108864);       // 4096x4096 bf16
  bf16* qkv    = (bf16*)(ws + 100663296);      // 2048x6144 bf16
  bf16* attn   = (bf16*)(ws + 125829120);      // 2048x4096 bf16

  cvt3<<<24576, 256, 0, stream>>>(hidden, hid_b, 8388608,
                                  w_qkv, wqkv_b, 25165824,
                                  w_o, wo_b);
  gemm_qkv<<<dim3(16, 16), 512, 0, stream>>>(hid_b, wqkv_b, qkv, 2048, 6144, 4096);
  rope_kernel<<<2560, 256, 0, stream>>>(qkv, positions);
  attn_kernel<<<dim3(8, 32), 512, 0, stream>>>(qkv, attn);
  gemm_out<<<dim3(16, 16), 512, 0, stream>>>(attn, wo_b, out, 2048, 4096, 4096);
}

// Round 6
// 488.353 us; speedup vs baseline: 1.1319x; 1.0352x over previous
//
#include <hip/hip_runtime.h>
#include <hip/hip_bf16.h>
#include <cstdint>

typedef __bf16 bf16;
typedef __bf16 bf16x8 __attribute__((ext_vector_type(8)));
typedef float f32x4 __attribute__((ext_vector_type(4)));

#define DEV __device__ __forceinline__

DEV f32x4 mfma16(bf16x8 a, bf16x8 b, f32x4 c) {
  return __builtin_amdgcn_mfma_f32_16x16x32_bf16(a, b, c, 0, 0, 0);
}

DEV void gl2lds16(const void* g, void* l) {
  __builtin_amdgcn_global_load_lds((__attribute__((address_space(1))) void*)g,
                                   (__attribute__((address_space(3))) void*)l,
                                   16, 0, 0);
}

#define VMWAIT(N) asm volatile("s_waitcnt vmcnt(" #N ")" ::: "memory")

// ---------------- fused fp32 -> bf16 convert, 3 segments ----------------
DEV void cvt8(const float* __restrict__ s, bf16* __restrict__ d) {
  f32x4 a = *(const f32x4*)(s);
  f32x4 b = *(const f32x4*)(s + 4);
  bf16x8 o;
#pragma unroll
  for (int e = 0; e < 4; ++e) { o[e] = (bf16)a[e]; o[e + 4] = (bf16)b[e]; }
  *(bf16x8*)(d) = o;
}

__global__ void cvt3(const float* __restrict__ s0, bf16* __restrict__ d0, int n0,
                     const float* __restrict__ s1, bf16* __restrict__ d1, int n1,
                     const float* __restrict__ s2, bf16* __restrict__ d2) {
  long i = ((long)blockIdx.x * 256 + threadIdx.x) * 8;
  if (i < n0) { cvt8(s0 + i, d0 + i); return; }
  i -= n0;
  if (i < n1) { cvt8(s1 + i, d1 + i); return; }
  i -= n1;
  cvt8(s2 + i, d2 + i);
}

// ---------------- GEMM qkv: C = A(MxK) * B(NxK)^T, 128x384 tile ----------------
// grid (16,16) = 256 blocks = 1 per CU. 512 threads = 8 waves (2M x 4N),
// per-wave 64x96 output (acc[4][6]). Phase-pipelined K=32 slices; LDS = 4
// rotating 32KiB regions; counted vmcnt(8) (3 regions / 12 loads in flight).
// v7: no mid-phase lgkmcnt(0) drain -- ds_reads are normal loads, the
// compiler schedules fine-grained counted lgkm waits so MFMA k can start as
// soon as its own operands land. Trailing lgkmcnt(0) (free in steady state)
// preserves the invariant: no wave passes the next barrier with LDS reads
// pending, so stage(p+3) into region (p-1)&3 can't race phase-(p-1) reads.
__global__ __launch_bounds__(512, 2) void gemm_qkv(const bf16* __restrict__ A,
                                                   const bf16* __restrict__ B,
                                                   bf16* __restrict__ C, int M, int N, int K) {
  __shared__ char lds[131072];  // 4 regions x 32 KiB
  const int tid = threadIdx.x;
  const int lane = tid & 63, w = tid >> 6;
  const int wm = w >> 2, wn = w & 3;  // 2 x 4 waves
  const int quad = lane >> 4, r = lane & 15;
  const long mBase = (long)blockIdx.y * 128, nBase = (long)blockIdx.x * 384;
  const int G = K >> 5;  // number of K=32 phases

  // region = 2048 16B chunks: A chunks [0,512): row=c>>2; B chunks [512,2048):
  // row=(c-512)>>2.  phys slot=c&3, logical k-chunk = slot ^ ((row>>1)&3).
  const bf16* src[4];
#pragma unroll
  for (int i = 0; i < 4; ++i) {
    const int c = i * 512 + tid;
    const int partB = (c >= 512);
    const int rb = partB ? (c - 512) : c;
    const int row = rb >> 2, slot = rb & 3;
    const int kc = slot ^ ((row >> 1) & 3);
    const bf16* base = partB ? (B + (nBase + row) * (long)K)
                             : (A + (mBase + row) * (long)K);
    src[i] = base + kc * 8;
  }

  const int pslot = (quad ^ ((r >> 1) & 3)) << 4;
  const int offA = (wm * 64 + r) * 64 + pslot;                 // + mi*1024
  const int offB = 8192 + (wn * 96 + r) * 64 + pslot;          // + ni*1024

  f32x4 acc[4][6];
#pragma unroll
  for (int i = 0; i < 4; ++i)
#pragma unroll
    for (int j = 0; j < 6; ++j) acc[i][j] = f32x4{0.f, 0.f, 0.f, 0.f};

  auto stage = [&](int p) {
    char* db = lds + ((p & 3) << 15);
    const long ko = (long)p * 32;
#pragma unroll
    for (int i = 0; i < 4; ++i)
      gl2lds16(src[i] + ko, db + (i * 512 + w * 64) * 16);
  };

  auto phase = [&](int p, bool do_stage) {
    __builtin_amdgcn_s_barrier();
    __builtin_amdgcn_sched_barrier(0);   // no ds_read hoisted above the barrier
    char* rb = lds + ((p & 3) << 15);
    bf16x8 af[4], bfr[6];
#pragma unroll
    for (int mi = 0; mi < 4; ++mi) af[mi] = *(const bf16x8*)(rb + offA + mi * 1024);
#pragma unroll
    for (int ni = 0; ni < 6; ++ni) bfr[ni] = *(const bf16x8*)(rb + offB + ni * 1024);
    if (do_stage) stage(p + 3);
    __builtin_amdgcn_s_setprio(1);
#pragma unroll
    for (int mi = 0; mi < 4; ++mi)
#pragma unroll
      for (int ni = 0; ni < 6; ++ni)
        acc[mi][ni] = mfma16(af[mi], bfr[ni], acc[mi][ni]);
    __builtin_amdgcn_s_setprio(0);
    asm volatile("s_waitcnt lgkmcnt(0)" ::: "memory");  // free; guards next barrier
  };

  stage(0); stage(1); stage(2);
  for (int p = 0; p < G - 3; ++p) { VMWAIT(8); phase(p, true); }
  VMWAIT(8); phase(G - 3, false);
  VMWAIT(4); phase(G - 2, false);
  VMWAIT(0); phase(G - 1, false);

#pragma unroll
  for (int mi = 0; mi < 4; ++mi)
#pragma unroll
    for (int ni = 0; ni < 6; ++ni)
#pragma unroll
      for (int rg = 0; rg < 4; ++rg) {
        long row = mBase + wm * 64 + mi * 16 + quad * 4 + rg;
        long col = nBase + wn * 96 + ni * 16 + r;
        C[row * N + col] = (bf16)acc[mi][ni][rg];
      }
}

// ---------------- GEMM out: C(f32) = A(MxK) * B(NxK)^T, 128x256 tile ----------------
// grid (16,16)=256 blocks, SPLIT=1, f32 output direct. Same v7 phase scheme.
// Region = A 128x32 (8 KiB) + B 256x32 (16 KiB) = 24 KiB; 4 regions = 96 KiB.
// 3 loads/thread/stage; 3 regions in flight -> steady wait vmcnt(6).
__global__ __launch_bounds__(512, 2) void gemm_out(const bf16* __restrict__ A,
                                                   const bf16* __restrict__ B,
                                                   float* __restrict__ C, int M, int N, int K) {
  __shared__ char lds[98304];
  const int tid = threadIdx.x;
  const int lane = tid & 63, w = tid >> 6;
  const int wm = w >> 2, wn = w & 3;  // 2 x 4 waves, per-wave 64x64
  const int quad = lane >> 4, r = lane & 15;
  const long mBase = (long)blockIdx.y * 128, nBase = (long)blockIdx.x * 256;
  const int G = K >> 5;

  const bf16* src[3];
#pragma unroll
  for (int i = 0; i < 3; ++i) {
    const int c = i * 512 + tid;
    const int partB = (c >= 512);
    const int rb = partB ? (c - 512) : c;   // A: [0,512), B: [0,1024)
    const int row = rb >> 2, slot = rb & 3;
    const int kc = slot ^ ((row >> 1) & 3);
    const bf16* base = partB ? (B + (nBase + row) * (long)K)
                             : (A + (mBase + row) * (long)K);
    src[i] = base + kc * 8;
  }

  const int pslot = (quad ^ ((r >> 1) & 3)) << 4;
  const int offA = (wm * 64 + r) * 64 + pslot;             // + mi*1024
  const int offB = 8192 + (wn * 64 + r) * 64 + pslot;      // + ni*1024

  f32x4 acc[4][4];
#pragma unroll
  for (int i = 0; i < 4; ++i)
#pragma unroll
    for (int j = 0; j < 4; ++j) acc[i][j] = f32x4{0.f, 0.f, 0.f, 0.f};

  auto stage = [&](int p) {
    char* db = lds + (p & 3) * 24576;
    const long ko = (long)p * 32;
    gl2lds16(src[0] + ko, db + (w * 64) * 16);
    gl2lds16(src[1] + ko, db + 8192 + (w * 64) * 16);
    gl2lds16(src[2] + ko, db + 8192 + (512 + w * 64) * 16);
  };

  auto phase = [&](int p, bool do_stage) {
    __builtin_amdgcn_s_barrier();
    __builtin_amdgcn_sched_barrier(0);
    char* rbuf = lds + (p & 3) * 24576;
    bf16x8 af[4], bfr[4];
#pragma unroll
    for (int mi = 0; mi < 4; ++mi) af[mi] = *(const bf16x8*)(rbuf + offA + mi * 1024);
#pragma unroll
    for (int ni = 0; ni < 4; ++ni) bfr[ni] = *(const bf16x8*)(rbuf + offB + ni * 1024);
    if (do_stage) stage(p + 3);
    __builtin_amdgcn_s_setprio(1);
#pragma unroll
    for (int mi = 0; mi < 4; ++mi)
#pragma unroll
      for (int ni = 0; ni < 4; ++ni)
        acc[mi][ni] = mfma16(af[mi], bfr[ni], acc[mi][ni]);
    __builtin_amdgcn_s_setprio(0);
    asm volatile("s_waitcnt lgkmcnt(0)" ::: "memory");
  };

  stage(0); stage(1); stage(2);
  for (int p = 0; p < G - 3; ++p) { VMWAIT(6); phase(p, true); }
  VMWAIT(6); phase(G - 3, false);
  VMWAIT(3); phase(G - 2, false);
  VMWAIT(0); phase(G - 1, false);

#pragma unroll
  for (int mi = 0; mi < 4; ++mi)
#pragma unroll
    for (int ni = 0; ni < 4; ++ni)
#pragma unroll
      for (int rg = 0; rg < 4; ++rg) {
        long row = mBase + wm * 64 + mi * 16 + quad * 4 + rg;
        long col = nBase + wn * 64 + ni * 16 + r;
        C[row * N + col] = acc[mi][ni][rg];
      }
}

// ---------------- RoPE (neox), vectorized bf16x8 ----------------
__global__ void rope_kernel(bf16* __restrict__ qkv, const int* __restrict__ pos) {
  int idx = blockIdx.x * 256 + threadIdx.x;  // T*40*8 threads
  int g = idx & 7;
  int rest = idx >> 3;
  int head = rest % 40;
  int t = rest / 40;
  bf16* p = qkv + (long)t * 6144 + head * 128 + g * 8;
  bf16x8 a = *(const bf16x8*)(p);
  bf16x8 b = *(const bf16x8*)(p + 64);
  const float pf = (float)pos[t];
  bf16x8 oa, ob;
#pragma unroll
  for (int e = 0; e < 8; ++e) {
    const int d = g * 8 + e;
    const float invf = __builtin_expf(-(float)d * (9.210340371976184f / 64.0f));
    const float fr = pf * invf;
    const float c = __builtin_cosf(fr), s = __builtin_sinf(fr);
    const float x1 = (float)a[e], x2 = (float)b[e];
    oa[e] = (bf16)(x1 * c - x2 * s);
    ob[e] = (bf16)(x2 * c + x1 * s);
  }
  *(bf16x8*)(p) = oa;
  *(bf16x8*)(p + 64) = ob;
}

// ---------------- flash attention v6b: QBLK=128, 8 waves, defer-max ----------------
__global__ __launch_bounds__(512, 2) void attn_kernel(const bf16* __restrict__ qkv,
                                                      bf16* __restrict__ out) {
  constexpr int LDV = 72, LDP = 72;
  constexpr float SCL2 = 0.08838834764831845f * 1.4426950408889634f;  // 1/sqrt(128)*log2(e)
  __shared__ bf16 Ks[2][64 * 128];   // [kv][d], chunk-XOR (phys = logical^(row&15))
  __shared__ bf16 Vt[2][128 * LDV];  // V^T [d][kv(+pad)], col-chunk XOR
  __shared__ bf16 Ps[128 * LDP];
  const int tid = threadIdx.x;
  const int lane = tid & 63, w = tid >> 6;
  const int quad = lane >> 4, r = lane & 15;
  const int pr = blockIdx.x, h = blockIdx.y;
  const int kvh = h >> 2;

  bf16x8 kreg[2], vreg[2];
  int srow[2], sdc[2];
#pragma unroll
  for (int ii = 0; ii < 2; ++ii) {
    const int c = ii * 512 + tid;   // 1024 chunks of 8 bf16 cover 64x128
    srow[ii] = c >> 4;
    sdc[ii] = c & 15;
  }

  for (int which = 0; which < 2; ++which) {
    const int qc = which ? (15 - pr) : pr;
    const int rowq = qc * 128 + w * 16;

    bf16x8 qf[4];
#pragma unroll
    for (int ks = 0; ks < 4; ++ks)
      qf[ks] = *(const bf16x8*)(qkv + (long)(rowq + r) * 6144 + h * 128 + ks * 32 + quad * 8);

    f32x4 of[8];
#pragma unroll
    for (int di = 0; di < 8; ++di) of[di] = f32x4{0.f, 0.f, 0.f, 0.f};
    float mrun[4], lrun[4];
#pragma unroll
    for (int rg = 0; rg < 4; ++rg) { mrun[rg] = -__builtin_inff(); lrun[rg] = 0.f; }

    const int ntiles = 2 * qc + 2;
#pragma unroll
    for (int ii = 0; ii < 2; ++ii) {
      const long rb = (long)srow[ii] * 6144 + kvh * 128;
      kreg[ii] = *(const bf16x8*)(qkv + rb + 4096 + sdc[ii] * 8);
      vreg[ii] = *(const bf16x8*)(qkv + rb + 5120 + sdc[ii] * 8);
    }

    for (int kt = 0; kt < ntiles; ++kt) {
      const int kvbase = kt * 64;
      const int buf = kt & 1;
#pragma unroll
      for (int ii = 0; ii < 2; ++ii) {
        const int row = srow[ii], dc = sdc[ii];
        *(bf16x8*)(&Ks[buf][row * 128 + ((dc ^ (row & 15)) << 3)]) = kreg[ii];
        const int pc = (((row >> 3) ^ (dc & 7)) << 3) + (row & 7);
#pragma unroll
        for (int e = 0; e < 8; ++e) Vt[buf][(dc * 8 + e) * LDV + pc] = vreg[ii][e];
      }
      {
        const int kvn = (kt + 1 < ntiles) ? (kt + 1) * 64 : kt * 64;
#pragma unroll
        for (int ii = 0; ii < 2; ++ii) {
          const long rb = (long)(kvn + srow[ii]) * 6144 + kvh * 128;
          kreg[ii] = *(const bf16x8*)(qkv + rb + 4096 + sdc[ii] * 8);
          vreg[ii] = *(const bf16x8*)(qkv + rb + 5120 + sdc[ii] * 8);
        }
      }
      __syncthreads();  // the only barrier per tile

      f32x4 sacc[4];
#pragma unroll
      for (int ni = 0; ni < 4; ++ni) sacc[ni] = f32x4{0.f, 0.f, 0.f, 0.f};
      __builtin_amdgcn_s_setprio(1);
#pragma unroll
      for (int ks = 0; ks < 4; ++ks) {
        bf16x8 kf[4];
#pragma unroll
        for (int ni = 0; ni < 4; ++ni)
          kf[ni] = *(const bf16x8*)(&Ks[buf][(ni * 16 + r) * 128 + (((ks * 4 + quad) ^ r) << 3)]);
#pragma unroll
        for (int ni = 0; ni < 4; ++ni) sacc[ni] = mfma16(qf[ks], kf[ni], sacc[ni]);
      }
      __builtin_amdgcn_s_setprio(0);

      float mt[4];
#pragma unroll
      for (int rg = 0; rg < 4; ++rg) mt[rg] = -1e30f;
      if (kvbase + 63 > rowq) {  // tile max kv exceeds wave's first row: mask
        const int rq = rowq + quad * 4;
#pragma unroll
        for (int ni = 0; ni < 4; ++ni) {
          const int ck = kvbase + ni * 16 + r;
#pragma unroll
          for (int rg = 0; rg < 4; ++rg) {
            float sv = sacc[ni][rg];
            sv = (ck > rq + rg) ? -1e30f : sv;
            sacc[ni][rg] = sv;
            mt[rg] = fmaxf(mt[rg], sv);
          }
        }
      } else {
#pragma unroll
        for (int ni = 0; ni < 4; ++ni)
#pragma unroll
          for (int rg = 0; rg < 4; ++rg) mt[rg] = fmaxf(mt[rg], sacc[ni][rg]);
      }
#pragma unroll
      for (int rg = 0; rg < 4; ++rg) {
        float v = mt[rg];
        v = fmaxf(v, __shfl_xor(v, 1));
        v = fmaxf(v, __shfl_xor(v, 2));
        v = fmaxf(v, __shfl_xor(v, 4));
        v = fmaxf(v, __shfl_xor(v, 8));
        mt[rg] = v;
      }
      // T13 defer-max: skip O/l rescale unless the tile max grew past THR=10
      const bool grew = (mt[0] > mrun[0] + 10.f) || (mt[1] > mrun[1] + 10.f) ||
                        (mt[2] > mrun[2] + 10.f) || (mt[3] > mrun[3] + 10.f);
      if (__any(grew)) {
        float alpha[4];
#pragma unroll
        for (int rg = 0; rg < 4; ++rg) {
          const float mnew = fmaxf(mrun[rg], mt[rg]);
          alpha[rg] = __builtin_exp2f((mrun[rg] - mnew) * SCL2);
          mrun[rg] = mnew;
          lrun[rg] *= alpha[rg];
        }
#pragma unroll
        for (int di = 0; di < 8; ++di)
#pragma unroll
          for (int rg = 0; rg < 4; ++rg) of[di][rg] *= alpha[rg];
      }
      float rsum[4];
#pragma unroll
      for (int rg = 0; rg < 4; ++rg) rsum[rg] = 0.f;
#pragma unroll
      for (int ni = 0; ni < 4; ++ni)
#pragma unroll
        for (int rg = 0; rg < 4; ++rg) {
          const float pv = __builtin_exp2f((sacc[ni][rg] - mrun[rg]) * SCL2);
          rsum[rg] += pv;
          Ps[(w * 16 + quad * 4 + rg) * LDP + ni * 16 + r] = (bf16)pv;
        }
#pragma unroll
      for (int rg = 0; rg < 4; ++rg) {
        float v = rsum[rg];
        v += __shfl_xor(v, 1);
        v += __shfl_xor(v, 2);
        v += __shfl_xor(v, 4);
        v += __shfl_xor(v, 8);
        lrun[rg] += v;
      }

      __builtin_amdgcn_s_setprio(1);
#pragma unroll
      for (int js = 0; js < 2; ++js) {
        const bf16x8 pf = *(const bf16x8*)(&Ps[(w * 16 + r) * LDP + js * 32 + quad * 8]);
#pragma unroll
        for (int di = 0; di < 8; ++di) {
          const int vrow = di * 16 + r;
          const int vcol = (((js * 4 + quad) ^ ((vrow >> 3) & 7)) << 3);
          const bf16x8 vf = *(const bf16x8*)(&Vt[buf][vrow * LDV + vcol]);
          of[di] = mfma16(pf, vf, of[di]);
        }
      }
      __builtin_amdgcn_s_setprio(0);
    }

#pragma unroll
    for (int rg = 0; rg < 4; ++rg) {
      const float inv = 1.f / lrun[rg];
      const long t = rowq + quad * 4 + rg;
#pragma unroll
      for (int di = 0; di < 8; ++di)
        out[t * 4096 + h * 128 + di * 16 + r] = (bf16)(of[di][rg] * inv);
    }
    __syncthreads();  // chunk boundary: all reads of LDS buffers done before restaging
  }
}

// ---------------- host ----------------
extern "C" void kernel_launch(void* const* d_in, const int* in_sizes, int n_in,
                              void* d_out, int out_size, void* d_ws, size_t ws_size,
                              hipStream_t stream) {
  const int* positions = (const int*)d_in[0];
  const float* hidden = (const float*)d_in[1];
  const float* w_qkv = (const float*)d_in[2];
  const float* w_o = (const float*)d_in[3];
  float* out = (float*)d_out;

  char* ws = (char*)d_ws;
  bf16* hid_b  = (bf16*)(ws);                  // 2048x4096 bf16 (dead after gemm_qkv)
  bf16* wqkv_b = (bf16*)(ws + 16777216);       // 6144x4096 bf16 (dead after gemm_qkv)
  bf16* wo_b   = (bf16*)(ws + 67108864);       // 4096x4096 bf16
  bf16* qkv    = (bf16*)(ws + 100663296);      // 2048x6144 bf16
  bf16* attn   = (bf16*)(ws + 125829120);      // 2048x4096 bf16

  cvt3<<<24576, 256, 0, stream>>>(hidden, hid_b, 8388608,
                                  w_qkv, wqkv_b, 25165824,
                                  w_o, wo_b);
  gemm_qkv<<<dim3(16, 16), 512, 0, stream>>>(hid_b, wqkv_b, qkv, 2048, 6144, 4096);
  rope_kernel<<<2560, 256, 0, stream>>>(qkv, positions);
  attn_kernel<<<dim3(8, 32), 512, 0, stream>>>(qkv, attn);
  gemm_out<<<dim3(16, 16), 512, 0, stream>>>(attn, wo_b, out, 2048, 4096, 4096);
}